// Round 4
// baseline (208.756 us; speedup 1.0000x reference)
//
#include <hip/hip_runtime.h>

#define VOCAB 67
#define EMB 50
#define NUM_LAYERS 8

typedef float floatx4 __attribute__((ext_vector_type(4)));  // native vec for nontemporal builtin

// Kernel 1: build the 67x67 logit lookup table.
// One block per vocab id v, 256 threads: 4 groups of 64 lanes split the
// K-dimension (e) 13/13/13/11, partials reduced through LDS. Cuts the
// serial per-layer FMA chain ~4x vs the 1-wave version.
__global__ void build_table(const float* __restrict__ emb,
                            const float* __restrict__ kappa,
                            const float* __restrict__ phi,
                            const float* __restrict__ W_out,
                            const float* __restrict__ b_out,
                            float* __restrict__ table) {
    __shared__ float ar[EMB], ai[EMB];
    __shared__ float psr[4][EMB], psi[4][EMB];
    __shared__ float inten[EMB];
    const int v = blockIdx.x;
    const int t = threadIdx.x;   // 0..255
    const int f = t & 63;        // output index within layer
    const int g = t >> 6;        // K-split group 0..3

    if (t < EMB) { ar[t] = emb[v * EMB + t]; ai[t] = 0.f; }
    __syncthreads();

    const int e0 = g * 13;
    const int e1 = (e0 + 13 < EMB) ? e0 + 13 : EMB;  // 13,13,13,11

    for (int l = 0; l < NUM_LAYERS; ++l) {
        if (f < EMB) {
            const float* k = kappa + l * EMB * EMB;
            const float* p = phi   + l * EMB * EMB;
            float sr = 0.f, si = 0.f;
            #pragma unroll 13
            for (int e = e0; e < e1; ++e) {
                float a_r = ar[e], a_i = ai[e];
                float kk = k[e * EMB + f];
                float pp = p[e * EMB + f];
                sr = fmaf(a_r, kk, sr);
                sr = fmaf(-a_i, pp, sr);
                si = fmaf(a_r, pp, si);
                si = fmaf(a_i, kk, si);
            }
            psr[g][f] = sr; psi[g][f] = si;
        }
        __syncthreads();
        if (t < EMB) {
            ar[t] = (psr[0][t] + psr[1][t]) + (psr[2][t] + psr[3][t]);
            ai[t] = (psi[0][t] + psi[1][t]) + (psi[2][t] + psi[3][t]);
        }
        __syncthreads();
    }

    if (t < EMB) inten[t] = ar[t] * ar[t] + ai[t] * ai[t];
    __syncthreads();

    if (t < VOCAB) {
        float s = b_out[t];
        #pragma unroll 10
        for (int e = 0; e < EMB; ++e)
            s = fmaf(inten[e], W_out[e * VOCAB + t], s);
        table[v * VOCAB + t] = s;
    }
}

// Kernel 2: out[row, :] = table[seq[row], :], written as float4 chunks.
// Branchless wrap handling (a 4-float chunk crosses at most one row
// boundary since 4 < 67); nontemporal dwordx4 stores (write-only output,
// keep L2 for the table/seq).
__global__ void gather_logits(const int* __restrict__ seq,
                              const float* __restrict__ table,
                              floatx4* __restrict__ out,
                              unsigned int n4, unsigned int nrows) {
    __shared__ float lut[VOCAB * VOCAB];
    for (int i = threadIdx.x; i < VOCAB * VOCAB; i += blockDim.x)
        lut[i] = table[i];
    __syncthreads();

    const unsigned int stride = gridDim.x * blockDim.x;
    for (unsigned int c = blockIdx.x * blockDim.x + threadIdx.x; c < n4; c += stride) {
        const unsigned int e = c * 4u;
        const unsigned int r0 = e / VOCAB;          // magic-multiply div
        const unsigned int col0 = e - r0 * VOCAB;
        unsigned int r1 = r0 + 1u;
        if (r1 >= nrows) r1 = nrows - 1u;           // wrap never actually uses OOB row
        const int b0 = seq[r0] * VOCAB;
        const int b1 = seq[r1] * VOCAB;

        const unsigned int c1 = col0 + 1u, c2 = col0 + 2u, c3 = col0 + 3u;
        floatx4 v;
        v.x = lut[b0 + (int)col0];
        v.y = lut[c1 >= VOCAB ? b1 + (int)(c1 - VOCAB) : b0 + (int)c1];
        v.z = lut[c2 >= VOCAB ? b1 + (int)(c2 - VOCAB) : b0 + (int)c2];
        v.w = lut[c3 >= VOCAB ? b1 + (int)(c3 - VOCAB) : b0 + (int)c3];
        __builtin_nontemporal_store(v, &out[c]);
    }
}

extern "C" void kernel_launch(void* const* d_in, const int* in_sizes, int n_in,
                              void* d_out, int out_size, void* d_ws, size_t ws_size,
                              hipStream_t stream) {
    const int*   seq    = (const int*)  d_in[0];
    const float* emb    = (const float*)d_in[1];
    const float* kappa  = (const float*)d_in[2];
    const float* phi    = (const float*)d_in[3];
    const float* W_out  = (const float*)d_in[4];
    const float* b_out  = (const float*)d_in[5];
    float* out   = (float*)d_out;
    float* table = (float*)d_ws;   // 67*67*4 = 17,956 bytes

    build_table<<<dim3(VOCAB), dim3(256), 0, stream>>>(emb, kappa, phi, W_out, b_out, table);

    const unsigned int nrows = (unsigned int)in_sizes[0];      // 64*8192 rows
    const unsigned int n4    = (unsigned int)(out_size / 4);   // exactly divisible
    gather_logits<<<dim3(4096), dim3(256), 0, stream>>>(seq, table, (floatx4*)out, n4, nrows);
}

// Round 5
// 204.762 us; speedup vs baseline: 1.0195x; 1.0195x over previous
//
#include <hip/hip_runtime.h>

#define VOCAB 67
#define EMB 50
#define NUM_LAYERS 8

// Kernel 1: build the 67x67 logit lookup table.
// One block per vocab id v, 256 threads: 4 groups of 64 lanes split the
// K-dimension (e) 13/13/13/11, partials reduced through LDS. Cuts the
// serial per-layer FMA chain ~4x vs the 1-wave version.
__global__ void build_table(const float* __restrict__ emb,
                            const float* __restrict__ kappa,
                            const float* __restrict__ phi,
                            const float* __restrict__ W_out,
                            const float* __restrict__ b_out,
                            float* __restrict__ table) {
    __shared__ float ar[EMB], ai[EMB];
    __shared__ float psr[4][EMB], psi[4][EMB];
    __shared__ float inten[EMB];
    const int v = blockIdx.x;
    const int t = threadIdx.x;   // 0..255
    const int f = t & 63;        // output index within layer
    const int g = t >> 6;        // K-split group 0..3

    if (t < EMB) { ar[t] = emb[v * EMB + t]; ai[t] = 0.f; }
    __syncthreads();

    const int e0 = g * 13;
    const int e1 = (e0 + 13 < EMB) ? e0 + 13 : EMB;  // 13,13,13,11

    for (int l = 0; l < NUM_LAYERS; ++l) {
        if (f < EMB) {
            const float* k = kappa + l * EMB * EMB;
            const float* p = phi   + l * EMB * EMB;
            float sr = 0.f, si = 0.f;
            #pragma unroll 13
            for (int e = e0; e < e1; ++e) {
                float a_r = ar[e], a_i = ai[e];
                float kk = k[e * EMB + f];
                float pp = p[e * EMB + f];
                sr = fmaf(a_r, kk, sr);
                sr = fmaf(-a_i, pp, sr);
                si = fmaf(a_r, pp, si);
                si = fmaf(a_i, kk, si);
            }
            psr[g][f] = sr; psi[g][f] = si;
        }
        __syncthreads();
        if (t < EMB) {
            ar[t] = (psr[0][t] + psr[1][t]) + (psr[2][t] + psr[3][t]);
            ai[t] = (psi[0][t] + psi[1][t]) + (psi[2][t] + psi[3][t]);
        }
        __syncthreads();
    }

    if (t < EMB) inten[t] = ar[t] * ar[t] + ai[t] * ai[t];
    __syncthreads();

    if (t < VOCAB) {
        float s = b_out[t];
        #pragma unroll 10
        for (int e = 0; e < EMB; ++e)
            s = fmaf(inten[e], W_out[e * VOCAB + t], s);
        table[v * VOCAB + t] = s;
    }
}

// Kernel 2: out[row, :] = table[seq[row], :], written as float4 chunks.
// Branchless wrap handling (a 4-float chunk crosses at most one row
// boundary since 4 < 67); plain dwordx4 stores through L2 (nontemporal
// measured as a small regression in R4 — L2 write-combining wins).
__global__ void gather_logits(const int* __restrict__ seq,
                              const float* __restrict__ table,
                              float4* __restrict__ out,
                              unsigned int n4, unsigned int nrows) {
    __shared__ float lut[VOCAB * VOCAB];
    for (int i = threadIdx.x; i < VOCAB * VOCAB; i += blockDim.x)
        lut[i] = table[i];
    __syncthreads();

    const unsigned int stride = gridDim.x * blockDim.x;
    for (unsigned int c = blockIdx.x * blockDim.x + threadIdx.x; c < n4; c += stride) {
        const unsigned int e = c * 4u;
        const unsigned int r0 = e / VOCAB;          // magic-multiply div
        const unsigned int col0 = e - r0 * VOCAB;
        unsigned int r1 = r0 + 1u;
        if (r1 >= nrows) r1 = nrows - 1u;           // wrap never actually uses OOB row
        const int b0 = seq[r0] * VOCAB;
        const int b1 = seq[r1] * VOCAB;

        const unsigned int c1 = col0 + 1u, c2 = col0 + 2u, c3 = col0 + 3u;
        float4 v;
        v.x = lut[b0 + (int)col0];
        v.y = lut[c1 >= VOCAB ? b1 + (int)(c1 - VOCAB) : b0 + (int)c1];
        v.z = lut[c2 >= VOCAB ? b1 + (int)(c2 - VOCAB) : b0 + (int)c2];
        v.w = lut[c3 >= VOCAB ? b1 + (int)(c3 - VOCAB) : b0 + (int)c3];
        out[c] = v;
    }
}

extern "C" void kernel_launch(void* const* d_in, const int* in_sizes, int n_in,
                              void* d_out, int out_size, void* d_ws, size_t ws_size,
                              hipStream_t stream) {
    const int*   seq    = (const int*)  d_in[0];
    const float* emb    = (const float*)d_in[1];
    const float* kappa  = (const float*)d_in[2];
    const float* phi    = (const float*)d_in[3];
    const float* W_out  = (const float*)d_in[4];
    const float* b_out  = (const float*)d_in[5];
    float* out   = (float*)d_out;
    float* table = (float*)d_ws;   // 67*67*4 = 17,956 bytes

    build_table<<<dim3(VOCAB), dim3(256), 0, stream>>>(emb, kappa, phi, W_out, b_out, table);

    const unsigned int nrows = (unsigned int)in_sizes[0];      // 64*8192 rows
    const unsigned int n4    = (unsigned int)(out_size / 4);   // exactly divisible
    gather_logits<<<dim3(4096), dim3(256), 0, stream>>>(seq, table, (float4*)out, n4, nrows);
}